// Round 6
// baseline (100.492 us; speedup 1.0000x reference)
//
#include <hip/hip_runtime.h>
#include <math.h>

#define B 4
#define C 64
#define HW 4096

typedef _Float16 f16;
typedef f16 f16x8 __attribute__((ext_vector_type(8)));
typedef f16 f16x4 __attribute__((ext_vector_type(4)));
typedef float f32x4 __attribute__((ext_vector_type(4)));
typedef float f32x16 __attribute__((ext_vector_type(16)));
typedef f16x8 f16x8a __attribute__((aligned(8)));   // 8B-aligned vector loads

#define MFMA16(a,b,c) __builtin_amdgcn_mfma_f32_16x16x32_f16(a,b,c,0,0,0)
#define MFMA32(a,b,c) __builtin_amdgcn_mfma_f32_32x32x16_f16(a,b,c,0,0,0)

// ws layout (total ~20.2 MB):
//   et16   : [B][HW][C] f16  (e, i-major)        2 MB
//   ec16   : [B][C][HW] f16  (e, c-major)        2 MB
//   mbuf   : [B][HW] f32     (m_i = s_ii)        64 KB
//   rlbuf  : [B][HW] f32     (1/l_i)             64 KB
//   partial: [8][B][HW][C] f16  (out^T per iq)   16 MB

// XCD-affine swizzles (grid = 8 XCDs x k contiguous logical blocks).
__device__ __forceinline__ int swz_blk()    { int r = blockIdx.x; return (r & 7) * 32 + (r >> 3); }
__device__ __forceinline__ int swz_blk512() { int r = blockIdx.x; return (r & 7) * 64 + (r >> 3); }

// ---------------- Kernel A: e = W @ x + bconv -> et16 (i-major) + ec16 (c-major) ----
__global__ __launch_bounds__(256) void k_e(
    const float* __restrict__ x, const float* __restrict__ W,
    const float* __restrict__ bconv, f16* __restrict__ et, f16* __restrict__ ec)
{
  __shared__ float Ws[64][65];
  __shared__ float xs[64][64];
  __shared__ f16 es[64][72];
  const int blk = swz_blk();
  const int b = blk >> 6;
  const int i0 = (blk & 63) * 64;
  const int tid = threadIdx.x;

  for (int k = tid; k < 64 * 64; k += 256) Ws[k >> 6][k & 63] = W[k];
  for (int k = tid; k < 64 * 64; k += 256)
    xs[k >> 6][k & 63] = x[((size_t)b * C + (k >> 6)) * HW + i0 + (k & 63)];
  __syncthreads();

  const int o = tid & 63;
  const int ig = tid >> 6;
  float acc[16];
  float bv = bconv[o];
  #pragma unroll
  for (int k = 0; k < 16; ++k) acc[k] = bv;
  for (int c = 0; c < C; ++c) {
    float wv = Ws[o][c];
    #pragma unroll
    for (int k = 0; k < 16; ++k) acc[k] = fmaf(wv, xs[c][ig * 16 + k], acc[k]);
  }
  #pragma unroll
  for (int k = 0; k < 16; ++k) {
    int ii = ig * 16 + k;
    f16 v = (f16)acc[k];
    et[((size_t)b * HW + i0 + ii) * C + o] = v;
    es[o][ii] = v;
  }
  __syncthreads();
  const int ii = tid & 63, og = tid >> 6;
  #pragma unroll
  for (int k = 0; k < 16; ++k) {
    int oo = og * 16 + k;
    ec[((size_t)b * C + oo) * HW + i0 + ii] = es[oo][ii];
  }
}

// ---------------- Kernel B: m_i = s_ii, rl_i = 1/sum_j exp(s_ij - s_ii) -------------
// 256 blocks = (b:4, 64 i-blocks of 64 rows) x 1024 thr (16 waves -> 16 waves/CU).
// launch_bounds(1024) caps VGPR at 128; live state ~100 -> no spill.
__global__ __launch_bounds__(1024) void k_stats(
    const f16* __restrict__ et, float* __restrict__ mbuf, float* __restrict__ rlbuf)
{
  __shared__ float mdiag[64];
  __shared__ float lpart[16][68];
  const int blk = swz_blk();
  const int b = blk >> 6;
  const int i0 = (blk & 63) * 64;
  const int tid = threadIdx.x;
  const int wv = tid >> 6;
  const int lane = tid & 63;
  const int lr = lane & 15, lg = lane >> 4;
  const f16* etb = et + (size_t)b * HW * C;

  // A-fragments: the block's 64 i-rows (4 subtiles x 2 K-chunks)
  f16x8 a[4][2];
  #pragma unroll
  for (int is = 0; is < 4; ++is)
    #pragma unroll
    for (int kc = 0; kc < 2; ++kc)
      a[is][kc] = *(const f16x8*)(etb + (size_t)(i0 + is * 16 + lr) * C + kc * 32 + lg * 8);

  // diagonal s_ii (wave 0; A-frag == B-frag layout on the diagonal tile)
  if (wv == 0) {
    #pragma unroll
    for (int is = 0; is < 4; ++is) {
      f32x4 z = {0.f, 0.f, 0.f, 0.f};
      f32x4 D = MFMA16(a[is][0], a[is][0], z);
      D = MFMA16(a[is][1], a[is][1], D);
      #pragma unroll
      for (int r = 0; r < 4; ++r)
        if (lr == lg * 4 + r) mdiag[is * 16 + lr] = D[r];
    }
  }
  __syncthreads();

  float ms[4][4];
  #pragma unroll
  for (int is = 0; is < 4; ++is)
    #pragma unroll
    for (int r = 0; r < 4; ++r) ms[is][r] = mdiag[is * 16 + lg * 4 + r];

  float lacc[4][4] = {};
  for (int t = 0; t < 8; ++t) {
    const int j0 = (wv + 16 * t) * 32;
    f16x8 bj[2][2];
    #pragma unroll
    for (int js = 0; js < 2; ++js)
      #pragma unroll
      for (int kc = 0; kc < 2; ++kc)
        bj[js][kc] = *(const f16x8*)(etb + (size_t)(j0 + js * 16 + lr) * C + kc * 32 + lg * 8);
    #pragma unroll
    for (int js = 0; js < 2; ++js)
      #pragma unroll
      for (int is = 0; is < 4; ++is) {
        f32x4 z = {0.f, 0.f, 0.f, 0.f};
        f32x4 S = MFMA16(a[is][0], bj[js][0], z);
        S = MFMA16(a[is][1], bj[js][1], S);
        #pragma unroll
        for (int r = 0; r < 4; ++r) lacc[is][r] += __expf(S[r] - ms[is][r]);
      }
  }

  // reduce over the 16 j-columns held by lanes sharing lg
  #pragma unroll
  for (int m = 1; m < 16; m <<= 1)
    #pragma unroll
    for (int is = 0; is < 4; ++is)
      #pragma unroll
      for (int r = 0; r < 4; ++r) lacc[is][r] += __shfl_xor(lacc[is][r], m);

  if (lr == 0)
    #pragma unroll
    for (int is = 0; is < 4; ++is)
      #pragma unroll
      for (int r = 0; r < 4; ++r) lpart[wv][is * 16 + lg * 4 + r] = lacc[is][r];
  __syncthreads();

  if (tid < 64) {
    float l = 0.f;
    #pragma unroll
    for (int w = 0; w < 16; ++w) l += lpart[w][tid];
    rlbuf[(size_t)b * HW + i0 + tid] = 1.0f / l;
    mbuf[(size_t)b * HW + i0 + tid] = mdiag[tid];
  }
}

// ---------------- Kernel C: partial^T[iq] += P^T . e^T  (out^T = sum_i) -------------
// 512 blocks = (b:4, jb:16 of 256 j, iq:8 of 512 i). 512 thr = 8 waves, 32 j per wave.
// ~90 VGPR -> 2 blocks/CU = 16 waves/CU.
#define ETS 68   // etL row stride (f16)
#define ECS 36   // ecL row stride
#define PTS 36   // pt  row stride
__global__ __launch_bounds__(512, 4) void k_out(
    const f16* __restrict__ et, const f16* __restrict__ ec,
    const float* __restrict__ mbuf, const float* __restrict__ rlbuf,
    f16* __restrict__ partial)
{
  __shared__ __align__(16) f16 etL[2][32][ETS];   // [i][c]
  __shared__ __align__(16) f16 ecL[2][64][ECS];   // [c][i]
  __shared__ __align__(16) f16 pt[8][32][PTS];    // wave-private P^T repack [j][i]
  __shared__ __align__(16) float mL[512];         // m for the block's 512 i
  __shared__ __align__(16) float rL[512];         // rl for the block's 512 i
  const int blk = swz_blk512();
  const int b  = blk >> 7;
  const int jb = (blk >> 3) & 15;
  const int iq = blk & 7;
  const int tid = threadIdx.x;
  const int w = tid >> 6;
  const int lane = tid & 63;
  const int l31 = lane & 31;
  const int h = lane >> 5;
  const int jbase = jb * 256 + w * 32;
  const int ibase = iq * 512;

  const f16* etb = et + (size_t)b * HW * C;
  const f16* ecb = ec + (size_t)b * C * HW;

  // stage m/rl for this block's i-range into LDS (one-time)
  mL[tid] = mbuf[(size_t)b * HW + ibase + tid];
  rL[tid] = rlbuf[(size_t)b * HW + ibase + tid];

  // score B fragments (regs, fixed): this wave's 32 j x 4 K-chunks of 16 c
  f16x8 bj[4];
  #pragma unroll
  for (int kc = 0; kc < 4; ++kc)
    bj[kc] = *(const f16x8*)(etb + (size_t)(jbase + l31) * C + kc * 16 + h * 8);

  f32x16 acc[2] = {};   // [cs] of out^T (m=j, n=c)

  // staging roles: threads 0..255 stage et chunk (32x64), 256..511 stage ec (64x32)
  const bool se = (tid < 256);
  const int sei = tid >> 3;
  const int sec = (tid & 7) * 8;
  const int scc = (tid & 255) >> 2;
  const int sci = (tid & 3) * 8;

  // prologue: stage chunk 0
  if (se) *(f16x8a*)&etL[0][sei][sec] = *(const f16x8*)(etb + (size_t)(ibase + sei) * C + sec);
  else    *(f16x8a*)&ecL[0][scc][sci] = *(const f16x8*)(ecb + (size_t)scc * HW + ibase + sci);
  __syncthreads();

  for (int t = 0; t < 16; ++t) {
    const int cur = t & 1;
    const int i0c = ibase + t * 32;

    // issue next chunk's global load early
    f16x8 sv;
    if (t < 15) {
      if (se) sv = *(const f16x8*)(etb + (size_t)(i0c + 32 + sei) * C + sec);
      else    sv = *(const f16x8*)(ecb + (size_t)scc * HW + (i0c + 32) + sci);
    }

    // PV B fragments (e^T): B[k=i][n=c] from ecL
    f16x8 bv[2][2];
    #pragma unroll
    for (int cs = 0; cs < 2; ++cs)
      #pragma unroll
      for (int kf = 0; kf < 2; ++kf)
        bv[cs][kf] = *(const f16x8a*)&ecL[cur][cs * 32 + l31][kf * 16 + h * 8];

    // score A fragments: A[m=i][k=c] from etL
    f16x8 af[4];
    #pragma unroll
    for (int kc = 0; kc < 4; ++kc)
      af[kc] = *(const f16x8a*)&etL[cur][l31][kc * 16 + h * 8];

    f32x16 z = {};
    f32x16 S = MFMA32(af[0], bj[0], z);
    S = MFMA32(af[1], bj[1], S);
    S = MFMA32(af[2], bj[2], S);
    S = MFMA32(af[3], bj[3], S);

    // P = exp(S - m_i) * rl_i -> wave-private pt[j][i]
    // (S lane map: col j = l31, row i = (r&3)+8*(r>>2)+4h)
    const int tb = t * 32;
    #pragma unroll
    for (int rq = 0; rq < 4; ++rq) {
      f32x4 m4 = *(const f32x4*)&mL[tb + 8 * rq + 4 * h];
      f32x4 r4 = *(const f32x4*)&rL[tb + 8 * rq + 4 * h];
      f16x4 pv;
      #pragma unroll
      for (int rr = 0; rr < 4; ++rr)
        pv[rr] = (f16)(__expf(S[rq * 4 + rr] - m4[rr]) * r4[rr]);
      *(f16x4*)&pt[w][l31][8 * rq + 4 * h] = pv;
    }
    // read back as PV A-frags: A[m=j][k=i]
    f16x8 pa0 = *(const f16x8a*)&pt[w][l31][h * 8];
    f16x8 pa1 = *(const f16x8a*)&pt[w][l31][16 + h * 8];
    acc[0] = MFMA32(pa0, bv[0][0], acc[0]);
    acc[1] = MFMA32(pa0, bv[1][0], acc[1]);
    acc[0] = MFMA32(pa1, bv[0][1], acc[0]);
    acc[1] = MFMA32(pa1, bv[1][1], acc[1]);

    // stage write for next chunk
    if (t < 15) {
      if (se) *(f16x8a*)&etL[cur ^ 1][sei][sec] = sv;
      else    *(f16x8a*)&ecL[cur ^ 1][scc][sci] = sv;
    }
    __syncthreads();
  }

  // partial[iq][b][j][c] (out^T layout -> coalesced: lanes vary c)
  f16* pb = partial + (size_t)(iq * B + b) * HW * C;
  #pragma unroll
  for (int cs = 0; cs < 2; ++cs)
    #pragma unroll
    for (int r = 0; r < 16; ++r) {
      int j = jbase + (r & 3) + 8 * (r >> 2) + 4 * h;
      pb[(size_t)j * C + cs * 32 + l31] = (f16)acc[cs][r];
    }
}

// ---------------- Kernel D: out[c][j] = x + sum_iq partial[iq][j][c] (transpose) ----
__global__ __launch_bounds__(256) void k_reduce(
    const f16* __restrict__ partial, const float* __restrict__ x, float* __restrict__ out)
{
  __shared__ float tile[64][65];
  const int blk = swz_blk();
  const int b = blk >> 6;
  const int j0 = (blk & 63) * 64;
  const int tid = threadIdx.x;
  const int jj = tid >> 2, cq = (tid & 3) * 16;

  float a0[16] = {};
  for (int iq = 0; iq < 8; ++iq) {
    const f16* p = partial + ((size_t)(iq * B + b) * HW + j0 + jj) * C + cq;
    f16x8 v0 = *(const f16x8*)p;
    f16x8 v1 = *(const f16x8*)(p + 8);
    #pragma unroll
    for (int e = 0; e < 8; ++e) { a0[e] += (float)v0[e]; a0[8 + e] += (float)v1[e]; }
  }
  #pragma unroll
  for (int e = 0; e < 16; ++e) tile[jj][cq + e] = a0[e];
  __syncthreads();

  const int c = tid >> 2, jq = (tid & 3) * 16;
  #pragma unroll
  for (int k = 0; k < 4; ++k) {
    size_t idx = ((size_t)b * C + c) * HW + j0 + jq + k * 4;
    float4 xv = *(const float4*)(x + idx);
    float4 ov;
    ov.x = tile[jq + k * 4 + 0][c] + xv.x;
    ov.y = tile[jq + k * 4 + 1][c] + xv.y;
    ov.z = tile[jq + k * 4 + 2][c] + xv.z;
    ov.w = tile[jq + k * 4 + 3][c] + xv.w;
    *(float4*)(out + idx) = ov;
  }
}

extern "C" void kernel_launch(void* const* d_in, const int* in_sizes, int n_in,
                              void* d_out, int out_size, void* d_ws, size_t ws_size,
                              hipStream_t stream) {
  const float* x = (const float*)d_in[0];
  const float* W = (const float*)d_in[1];
  const float* bconv = (const float*)d_in[2];
  float* out = (float*)d_out;

  f16* et16 = (f16*)d_ws;
  f16* ec16 = et16 + (size_t)B * HW * C;
  float* mbuf = (float*)(ec16 + (size_t)B * HW * C);
  float* rlbuf = mbuf + (size_t)B * HW;
  f16* partial = (f16*)(rlbuf + (size_t)B * HW);   // 16 MB; ws total ~20.2 MB

  k_e<<<dim3(256), dim3(256), 0, stream>>>(x, W, bconv, et16, ec16);
  k_stats<<<dim3(256), dim3(1024), 0, stream>>>(et16, mbuf, rlbuf);
  k_out<<<dim3(512), dim3(512), 0, stream>>>(et16, ec16, mbuf, rlbuf, partial);
  k_reduce<<<dim3(256), dim3(256), 0, stream>>>(partial, x, out);
}